// Round 7
// baseline (218.516 us; speedup 1.0000x reference)
//
#include <hip/hip_runtime.h>
#include <math.h>

#define DIM 256
#define HEADS 8
#define HD 32
// log2(e)/sqrt(32): folded into stored Q so attention uses native exp2
#define QSCALE 0.25504526770295183f

typedef __attribute__((ext_vector_type(8))) short bf16x8;
typedef __attribute__((ext_vector_type(4))) float f32x4;

#if __has_builtin(__builtin_amdgcn_exp2f)
#define EXP2(x) __builtin_amdgcn_exp2f(x)
#else
#define EXP2(x) __expf((x) * 0.6931471805599453f)
#endif

__device__ __forceinline__ unsigned short f2bf(float f) {
  unsigned int u = __float_as_uint(f);
  unsigned int r = u + 0x7fff + ((u >> 16) & 1);   // round-to-nearest-even
  return (unsigned short)(r >> 16);
}
__device__ __forceinline__ float bf2f(unsigned short u) {
  return __uint_as_float(((unsigned int)u) << 16);
}

// ---------------- prep: both avgpools + both weight cvts in one launch ----------
__global__ __launch_bounds__(256) void prep_kernel(const float* __restrict__ x,
    const float* __restrict__ pw_w, const float* __restrict__ fus_w,
    float* __restrict__ xs2, float* __restrict__ xs4,
    unsigned short* __restrict__ Wb, unsigned short* __restrict__ Wf) {
  const int gx = blockIdx.x, t = threadIdx.x;
  if (gx < 1024) {                                  // avgpool s=2 -> 256x32x32
    int id = gx * 256 + t;
    int c = id >> 10, n = id & 1023;
    int y = (n >> 5) << 1, x0 = (n & 31) << 1;
    const float* b = x + c * 4096 + y * 64 + x0;
    xs2[id] = (b[0] + b[1] + b[64] + b[65]) * 0.25f;
  } else if (gx < 1280) {                           // avgpool s=4 -> 256x16x16
    int id = (gx - 1024) * 256 + t;
    int c = id >> 8, n = id & 255;
    int y = (n >> 4) << 2, x0 = (n & 15) << 2;
    const float* b = x + c * 4096 + y * 64 + x0;
    float s = 0.f;
    #pragma unroll
    for (int dy = 0; dy < 4; ++dy)
      #pragma unroll
      for (int dx = 0; dx < 4; ++dx) s += b[dy * 64 + dx];
    xs4[id] = s * 0.0625f;
  } else if (gx < 1856) {                           // cvt pw_w -> Wb (589824 fl)
    int id = (gx - 1280) * 256 + t;
    float4 v = *(const float4*)(pw_w + id * 4);
    ushort4 st; st.x = f2bf(v.x); st.y = f2bf(v.y); st.z = f2bf(v.z); st.w = f2bf(v.w);
    *(ushort4*)(Wb + id * 4) = st;
  } else {                                          // cvt fus_w -> Wf (196608 fl)
    int id = (gx - 1856) * 256 + t;
    float4 v = *(const float4*)(fus_w + id * 4);
    ushort4 st; st.x = f2bf(v.x); st.y = f2bf(v.y); st.z = f2bf(v.z); st.w = f2bf(v.w);
    *(ushort4*)(Wf + id * 4) = st;
  }
}

// ---------------- dwconv (dw + pos), all 3 scales in one launch -----------------
__global__ __launch_bounds__(256) void dwconv_all_kernel(const float* __restrict__ x,
    const float* __restrict__ xs2, const float* __restrict__ xs4,
    const float* __restrict__ dw_w, const float* __restrict__ dw_b,
    const float* __restrict__ pos_w, const float* __restrict__ pos_b,
    float* __restrict__ xdwAll, float* __restrict__ posAll) {
  int gx = blockIdx.x;
  const float* src;
  int lgHs, wo, soff;
  if (gx < 4096)      { src = x;   lgHs = 6; wo = 0; soff = 0; }
  else if (gx < 5120) { src = xs2; lgHs = 5; wo = 1; soff = 1048576; gx -= 4096; }
  else                { src = xs4; lgHs = 4; wo = 2; soff = 1310720; gx -= 5120; }
  int Hs = 1 << lgHs;
  int Ns = Hs * Hs;
  int id = gx * 256 + threadIdx.x;                  // c * Ns + n  (within scale)
  int c = id >> (2 * lgHs);
  int n = id & (Ns - 1);
  int y = n >> lgHs, xx0 = n & (Hs - 1);
  const float* w1 = dw_w + wo * 2304 + c * 9;
  const float* w2 = pos_w + wo * 2304 + c * 9;
  const float* sb = src + c * Ns;
  float s1 = dw_b[wo * 256 + c], s2 = pos_b[wo * 256 + c];
  #pragma unroll
  for (int ky = 0; ky < 3; ++ky) {
    int yy = y + ky - 1;
    bool yok = (yy >= 0) && (yy < Hs);
    #pragma unroll
    for (int kx = 0; kx < 3; ++kx) {
      int xc = xx0 + kx - 1;
      bool ok = yok && (xc >= 0) && (xc < Hs);
      float v = ok ? sb[yy * Hs + xc] : 0.f;
      s1 += v * w1[ky * 3 + kx];
      s2 += v * w2[ky * 3 + kx];
    }
  }
  xdwAll[soff + id] = s1;
  posAll[soff + id] = s2;
}

// ---------------- transpose + cvt for all scales / both sources ----------------
// fp32 [256][Ns] -> bf16 [Ns][256]
__global__ __launch_bounds__(256) void transpose_all_kernel(const float* __restrict__ xdwAll,
    const float* __restrict__ posAll, unsigned short* __restrict__ xdwT,
    unsigned short* __restrict__ posT) {
  __shared__ unsigned short lds[64][72];
  int b = blockIdx.x;
  int N, soff, nx;
  if (b < 512)      { N = 4096; soff = 0;       nx = 64; }
  else if (b < 640) { N = 1024; soff = 1048576; nx = 16; b -= 512; }
  else              { N = 256;  soff = 1310720; nx = 4;  b -= 640; }
  const int z = b / (nx * 4);
  const int rem = b % (nx * 4);
  const int c0 = (rem / nx) * 64;
  const int n0 = (rem % nx) * 64;
  const float* src = (z ? posAll : xdwAll) + soff;
  unsigned short* dst = (z ? posT : xdwT) + soff;
  const int t = threadIdx.x;
  #pragma unroll
  for (int p = 0; p < 4; ++p) {
    int c = p * 16 + (t >> 4);
    int nn = (t & 15) * 4;
    float4 v = *(const float4*)(src + (size_t)(c0 + c) * N + n0 + nn);
    lds[nn + 0][c] = f2bf(v.x);
    lds[nn + 1][c] = f2bf(v.y);
    lds[nn + 2][c] = f2bf(v.z);
    lds[nn + 3][c] = f2bf(v.w);
  }
  __syncthreads();
  int n = t >> 2, seg = (t & 3) * 16;
  *(bf16x8*)(dst + (size_t)(n0 + n) * 256 + c0 + seg)     = *(const bf16x8*)&lds[n][seg];
  *(bf16x8*)(dst + (size_t)(n0 + n) * 256 + c0 + seg + 8) = *(const bf16x8*)&lds[n][seg + 8];
}

// ---------------- QKV GEMM via bf16 MFMA, all scales in one launch --------------
__global__ __launch_bounds__(256) void gemm_qkv_all(const unsigned short* __restrict__ WbA,
    const unsigned short* __restrict__ xdwTA, const float* __restrict__ biasA,
    const unsigned short* __restrict__ posTA, unsigned short* __restrict__ qkvTA,
    unsigned short* __restrict__ VbA) {
  int by = blockIdx.y;
  int Ns, tro;                                      // tro = element offset into xdwT/posT
  const unsigned short *Wb, *xdwT, *posT;
  unsigned short *qkvT, *Vb;
  const float* bias;
  if (by < 64) {
    Ns = 4096; tro = 0;
    Wb = WbA; bias = biasA; qkvT = qkvTA; Vb = VbA;
  } else if (by < 80) {
    Ns = 1024; tro = 1048576; by -= 64;
    Wb = WbA + 196608; bias = biasA + 768;
    qkvT = qkvTA + 2097152; Vb = VbA + 1048576;
  } else {
    Ns = 256; tro = 1310720; by -= 80;
    Wb = WbA + 393216; bias = biasA + 1536;
    qkvT = qkvTA + 2621440; Vb = VbA + 1310720;
  }
  xdwT = xdwTA + tro; posT = posTA + tro;
  const int t = threadIdx.x;
  const int wave = t >> 6, lane = t & 63;
  const int ln = lane & 15, quad = lane >> 4;
  const int o0 = blockIdx.x * 64 + (wave & 1) * 32;
  const int n0 = by * 64 + (wave >> 1) * 32;
  const unsigned short* a0 = Wb + (size_t)(o0 + ln) * 256 + quad * 8;
  const unsigned short* a1 = a0 + 16 * 256;
  const unsigned short* b0 = xdwT + (size_t)(n0 + ln) * 256 + quad * 8;
  const unsigned short* b1 = b0 + 16 * 256;
  f32x4 acc[2][2] = {};
  #pragma unroll
  for (int ks = 0; ks < 8; ++ks) {
    bf16x8 af0 = *(const bf16x8*)(a0 + ks * 32);
    bf16x8 af1 = *(const bf16x8*)(a1 + ks * 32);
    bf16x8 bv0 = *(const bf16x8*)(b0 + ks * 32);
    bf16x8 bv1 = *(const bf16x8*)(b1 + ks * 32);
    acc[0][0] = __builtin_amdgcn_mfma_f32_16x16x32_bf16(af0, bv0, acc[0][0], 0, 0, 0);
    acc[0][1] = __builtin_amdgcn_mfma_f32_16x16x32_bf16(af0, bv1, acc[0][1], 0, 0, 0);
    acc[1][0] = __builtin_amdgcn_mfma_f32_16x16x32_bf16(af1, bv0, acc[1][0], 0, 0, 0);
    acc[1][1] = __builtin_amdgcn_mfma_f32_16x16x32_bf16(af1, bv1, acc[1][1], 0, 0, 0);
  }
  const int cat = blockIdx.x >> 2;                  // 0=q 1=k 2=v
  #pragma unroll
  for (int mt = 0; mt < 2; ++mt) {
    int ot = o0 + mt * 16 + quad * 4;
    float bs0 = bias[ot], bs1 = bias[ot + 1], bs2 = bias[ot + 2], bs3 = bias[ot + 3];
    #pragma unroll
    for (int nt = 0; nt < 2; ++nt) {
      int nn = n0 + nt * 16 + ln;
      f32x4 v = acc[mt][nt];
      v.x += bs0; v.y += bs1; v.z += bs2; v.w += bs3;
      if (cat < 2) {
        ushort4 p4 = *(const ushort4*)(posT + (size_t)nn * 256 + (ot & 255));
        v.x += bf2f(p4.x); v.y += bf2f(p4.y); v.z += bf2f(p4.z); v.w += bf2f(p4.w);
        if (cat == 0) { v.x *= QSCALE; v.y *= QSCALE; v.z *= QSCALE; v.w *= QSCALE; }
        ushort4 st;
        st.x = f2bf(v.x); st.y = f2bf(v.y); st.z = f2bf(v.z); st.w = f2bf(v.w);
        *(ushort4*)(qkvT + (size_t)nn * 512 + ot) = st;
      } else {
        Vb[(size_t)(ot - 512 + 0) * Ns + nn] = f2bf(v.x);
        Vb[(size_t)(ot - 512 + 1) * Ns + nn] = f2bf(v.y);
        Vb[(size_t)(ot - 512 + 2) * Ns + nn] = f2bf(v.z);
        Vb[(size_t)(ot - 512 + 3) * Ns + nn] = f2bf(v.w);
      }
    }
  }
}

// ---------------- attention: all scales in one launch, low-reg body -------------
// z 0..7: s1 splits; z 8..15: s2 splits (x<8); z 16..19: s4 splits (x<2).
// Per-mt QK->exp->pack keeps only 8 score regs live; __launch_bounds__(256,4)
// asks the allocator for 4 waves/SIMD (<=128 unified VGPRs/wave).
__global__ __launch_bounds__(256, 4) void attn_all_kernel(
    const unsigned short* __restrict__ qkvTA, const unsigned short* __restrict__ VbA,
    unsigned short* __restrict__ accp1, unsigned short* __restrict__ p2,
    unsigned short* __restrict__ p4, float* __restrict__ ls1,
    float* __restrict__ ls2, float* __restrict__ ls4) {
  __shared__ unsigned short pt_lds[4 * 32 * 72];    // wave-private P^T [n][m], pad 72
  const int z = blockIdx.z;
  const unsigned short *qkvT, *Vb;
  unsigned short* accp;
  float* lsump;
  int Ns, lgMs, sp;
  if (z < 8) {
    qkvT = qkvTA; Vb = VbA; accp = accp1; lsump = ls1; Ns = 4096; lgMs = 9; sp = z;
  } else if (z < 16) {
    if (blockIdx.x >= 8) return;
    qkvT = qkvTA + 2097152; Vb = VbA + 1048576; accp = p2; lsump = ls2;
    Ns = 1024; lgMs = 7; sp = z - 8;
  } else {
    if (blockIdx.x >= 2) return;
    qkvT = qkvTA + 2621440; Vb = VbA + 1310720; accp = p4; lsump = ls4;
    Ns = 256; lgMs = 6; sp = z - 16;
  }
  const int t = threadIdx.x;
  const int wave = t >> 6, lane = t & 63;
  const int ln = lane & 15, quad = lane >> 4;
  const int h = blockIdx.y;
  const int n0 = blockIdx.x * 128 + wave * 32;
  const unsigned short* qb = qkvT + (size_t)n0 * 512 + h * 32 + quad * 8;
  bf16x8 qf0 = *(const bf16x8*)(qb + (size_t)ln * 512);
  bf16x8 qf1 = *(const bf16x8*)(qb + (size_t)(16 + ln) * 512);
  unsigned short* ptw = pt_lds + wave * (32 * 72);
  f32x4 acc[2][2] = {};
  float lsum0 = 0.f, lsum1 = 0.f;
  const f32x4 zero = {0.f, 0.f, 0.f, 0.f};
  const int m0s = sp << lgMs;
  const int nch = 1 << (lgMs - 6);
  const unsigned short* kb = qkvT + (size_t)(m0s + ln) * 512 + 256 + h * 32 + quad * 8;
  const unsigned short* vb = Vb + (size_t)(h * 32 + ln) * Ns + m0s + quad * 8;
  for (int ch = 0; ch < nch; ++ch) {
    const unsigned short* kc = kb + (size_t)ch * 64 * 512;
    const unsigned short* vc = vb + ch * 64;
    bf16x8 kf0 = *(const bf16x8*)(kc);
    bf16x8 kf1 = *(const bf16x8*)(kc + 16 * 512);
    bf16x8 kf2 = *(const bf16x8*)(kc + 32 * 512);
    bf16x8 kf3 = *(const bf16x8*)(kc + 48 * 512);
    bf16x8 vf00 = *(const bf16x8*)(vc);
    bf16x8 vf01 = *(const bf16x8*)(vc + 32);
    bf16x8 vf10 = *(const bf16x8*)(vc + (size_t)16 * Ns);
    bf16x8 vf11 = *(const bf16x8*)(vc + (size_t)16 * Ns + 32);
#define DO_MT(MT, KF)                                                            \
    {                                                                            \
      f32x4 s0 = __builtin_amdgcn_mfma_f32_16x16x32_bf16(KF, qf0, zero, 0, 0, 0);\
      f32x4 s1 = __builtin_amdgcn_mfma_f32_16x16x32_bf16(KF, qf1, zero, 0, 0, 0);\
      float e0 = EXP2(s0.x), e1 = EXP2(s0.y), e2 = EXP2(s0.z), e3 = EXP2(s0.w);  \
      lsum0 += (e0 + e1) + (e2 + e3);                                            \
      uint2 pk0;                                                                 \
      pk0.x = __builtin_amdgcn_perm(__float_as_uint(e1), __float_as_uint(e0), 0x07060302); \
      pk0.y = __builtin_amdgcn_perm(__float_as_uint(e3), __float_as_uint(e2), 0x07060302); \
      *(uint2*)&ptw[ln * 72 + MT * 16 + quad * 4] = pk0;                         \
      float f0 = EXP2(s1.x), f1 = EXP2(s1.y), f2 = EXP2(s1.z), f3 = EXP2(s1.w);  \
      lsum1 += (f0 + f1) + (f2 + f3);                                            \
      uint2 pk1;                                                                 \
      pk1.x = __builtin_amdgcn_perm(__float_as_uint(f1), __float_as_uint(f0), 0x07060302); \
      pk1.y = __builtin_amdgcn_perm(__float_as_uint(f3), __float_as_uint(f2), 0x07060302); \
      *(uint2*)&ptw[(16 + ln) * 72 + MT * 16 + quad * 4] = pk1;                  \
    }
    DO_MT(0, kf0)
    DO_MT(1, kf1)
    DO_MT(2, kf2)
    DO_MT(3, kf3)
#undef DO_MT
    #pragma unroll
    for (int ks = 0; ks < 2; ++ks) {
      bf16x8 pf0 = *(const bf16x8*)&ptw[ln * 72 + ks * 32 + quad * 8];
      bf16x8 pf1 = *(const bf16x8*)&ptw[(16 + ln) * 72 + ks * 32 + quad * 8];
      bf16x8 va = ks ? vf01 : vf00;
      bf16x8 vbf = ks ? vf11 : vf10;
      acc[0][0] = __builtin_amdgcn_mfma_f32_16x16x32_bf16(va, pf0, acc[0][0], 0, 0, 0);
      acc[0][1] = __builtin_amdgcn_mfma_f32_16x16x32_bf16(va, pf1, acc[0][1], 0, 0, 0);
      acc[1][0] = __builtin_amdgcn_mfma_f32_16x16x32_bf16(vbf, pf0, acc[1][0], 0, 0, 0);
      acc[1][1] = __builtin_amdgcn_mfma_f32_16x16x32_bf16(vbf, pf1, acc[1][1], 0, 0, 0);
    }
  }
  lsum0 += __shfl_xor(lsum0, 16, 64);
  lsum0 += __shfl_xor(lsum0, 32, 64);
  lsum1 += __shfl_xor(lsum1, 16, 64);
  lsum1 += __shfl_xor(lsum1, 32, 64);
  unsigned short* ap = accp + ((size_t)sp * 256 + h * 32) * Ns;
  #pragma unroll
  for (int dt = 0; dt < 2; ++dt) {
    #pragma unroll
    for (int r = 0; r < 4; ++r) {
      int cl = dt * 16 + quad * 4 + r;
      ap[(size_t)cl * Ns + n0 + ln]      = f2bf(((const float*)&acc[dt][0])[r]);
      ap[(size_t)cl * Ns + n0 + 16 + ln] = f2bf(((const float*)&acc[dt][1])[r]);
    }
  }
  if (lane < 16) {
    float* lp = lsump + ((size_t)sp * 8 + h) * Ns + n0;
    lp[lane]      = lsum0;
    lp[16 + lane] = lsum1;
  }
}

// ---------------- combine s2 (8 splits) + s4 (4 splits) in one launch -----------
__global__ __launch_bounds__(256) void combine24_kernel(const unsigned short* __restrict__ p2,
    const float* __restrict__ ls2, const unsigned short* __restrict__ p4,
    const float* __restrict__ ls4, float* __restrict__ out2, float* __restrict__ out4) {
  int id = blockIdx.x * 256 + threadIdx.x;
  if (id < 262144) {                                // s2: 256 x 1024
    int n = id & 1023, h = id >> 15;
    float v = 0.f, d = 0.f;
    #pragma unroll
    for (int sp = 0; sp < 8; ++sp) {
      v += bf2f(p2[sp * 262144 + id]);
      d += ls2[sp * 8192 + h * 1024 + n];
    }
    out2[id] = v / d;
  } else {                                          // s4: 256 x 256
    int idl = id - 262144;
    int n = idl & 255, h = idl >> 13;
    float v = 0.f, d = 0.f;
    #pragma unroll
    for (int sp = 0; sp < 4; ++sp) {
      v += bf2f(p4[sp * 65536 + idl]);
      d += ls4[sp * 2048 + h * 256 + n];
    }
    out4[idl] = v / d;
  }
}

// ---------------- build catT bf16 [4096][768] directly --------------------------
__global__ __launch_bounds__(256) void build_catT_kernel(const unsigned short* __restrict__ accp,
    const float* __restrict__ lsum1, const float* __restrict__ out2,
    const float* __restrict__ out4, unsigned short* __restrict__ catT) {
  __shared__ unsigned short lds[64][72];
  const int t = threadIdx.x;
  const int n0 = blockIdx.x * 64;
  const int by = blockIdx.y;
  const int c0 = by * 64;
  if (by < 4) {
    #pragma unroll
    for (int p = 0; p < 4; ++p) {
      int ct = p * 16 + (t >> 4);
      int c = c0 + ct;
      int h = c >> 5;
      int nn = (t & 15) * 4;
      float vs[4] = {0.f, 0.f, 0.f, 0.f};
      float ds[4] = {0.f, 0.f, 0.f, 0.f};
      #pragma unroll
      for (int sp = 0; sp < 8; ++sp) {
        ushort4 a = *(const ushort4*)(accp + (size_t)sp * 1048576 + (size_t)c * 4096 + n0 + nn);
        vs[0] += bf2f(a.x); vs[1] += bf2f(a.y); vs[2] += bf2f(a.z); vs[3] += bf2f(a.w);
        float4 dd = *(const float4*)(lsum1 + (size_t)sp * 32768 + (size_t)h * 4096 + n0 + nn);
        ds[0] += dd.x; ds[1] += dd.y; ds[2] += dd.z; ds[3] += dd.w;
      }
      lds[nn + 0][ct] = f2bf(vs[0] / ds[0]);
      lds[nn + 1][ct] = f2bf(vs[1] / ds[1]);
      lds[nn + 2][ct] = f2bf(vs[2] / ds[2]);
      lds[nn + 3][ct] = f2bf(vs[3] / ds[3]);
    }
  } else {
    const bool s2 = by < 8;
    const float* src = s2 ? out2 : out4;
    const int Hs = s2 ? 32 : 16;
    const int coff = s2 ? 256 : 512;
    const float sc = (float)Hs / 64.0f;
    #pragma unroll
    for (int p = 0; p < 4; ++p) {
      int ct = p * 16 + (t >> 4);
      const float* s = src + (size_t)(c0 - coff + ct) * Hs * Hs;
      int nn = (t & 15) * 4;
      #pragma unroll
      for (int i = 0; i < 4; ++i) {
        int n = n0 + nn + i;
        int y = n >> 6, x = n & 63;
        float fy = ((float)y + 0.5f) * sc - 0.5f;
        float fx = ((float)x + 0.5f) * sc - 0.5f;
        float fy0 = floorf(fy), fx0 = floorf(fx);
        int y0 = (int)fy0, x0 = (int)fx0;
        float ty = fy - fy0, tx = fx - fx0;
        int y0c = min(max(y0, 0), Hs - 1), y1c = min(max(y0 + 1, 0), Hs - 1);
        int x0c = min(max(x0, 0), Hs - 1), x1c = min(max(x0 + 1, 0), Hs - 1);
        float v00 = s[y0c * Hs + x0c], v01 = s[y0c * Hs + x1c];
        float v10 = s[y1c * Hs + x0c], v11 = s[y1c * Hs + x1c];
        float v0 = v00 + (v01 - v00) * tx;
        float v1 = v10 + (v11 - v10) * tx;
        lds[nn + i][ct] = f2bf(v0 + (v1 - v0) * ty);
      }
    }
  }
  __syncthreads();
  int n = t >> 2, seg = (t & 3) * 16;
  *(bf16x8*)(catT + (size_t)(n0 + n) * 768 + c0 + seg)     = *(const bf16x8*)&lds[n][seg];
  *(bf16x8*)(catT + (size_t)(n0 + n) * 768 + c0 + seg + 8) = *(const bf16x8*)&lds[n][seg + 8];
}

// ---------------- fusion GEMM via bf16 MFMA, split-K=3 --------------------------
__global__ __launch_bounds__(256) void gemm_fus_mfma(const unsigned short* __restrict__ Wf,
    const unsigned short* __restrict__ catT, float* __restrict__ part) {
  const int t = threadIdx.x;
  const int wave = t >> 6, lane = t & 63;
  const int ln = lane & 15, quad = lane >> 4;
  const int o0 = blockIdx.x * 64 + (wave & 1) * 32;
  const int n0 = blockIdx.y * 64 + (wave >> 1) * 32;
  const int sp = blockIdx.z;
  const int k0 = sp * 256;
  const unsigned short* a0 = Wf + (size_t)(o0 + ln) * 768 + k0 + quad * 8;
  const unsigned short* a1 = a0 + 16 * 768;
  const unsigned short* b0 = catT + (size_t)(n0 + ln) * 768 + k0 + quad * 8;
  const unsigned short* b1 = b0 + 16 * 768;
  f32x4 acc[2][2] = {};
  #pragma unroll
  for (int ks = 0; ks < 8; ++ks) {
    bf16x8 af0 = *(const bf16x8*)(a0 + ks * 32);
    bf16x8 af1 = *(const bf16x8*)(a1 + ks * 32);
    bf16x8 bv0 = *(const bf16x8*)(b0 + ks * 32);
    bf16x8 bv1 = *(const bf16x8*)(b1 + ks * 32);
    acc[0][0] = __builtin_amdgcn_mfma_f32_16x16x32_bf16(af0, bv0, acc[0][0], 0, 0, 0);
    acc[0][1] = __builtin_amdgcn_mfma_f32_16x16x32_bf16(af0, bv1, acc[0][1], 0, 0, 0);
    acc[1][0] = __builtin_amdgcn_mfma_f32_16x16x32_bf16(af1, bv0, acc[1][0], 0, 0, 0);
    acc[1][1] = __builtin_amdgcn_mfma_f32_16x16x32_bf16(af1, bv1, acc[1][1], 0, 0, 0);
  }
  float* pp = part + (size_t)sp * 1048576;
  #pragma unroll
  for (int mt = 0; mt < 2; ++mt) {
    #pragma unroll
    for (int nt = 0; nt < 2; ++nt) {
      #pragma unroll
      for (int r = 0; r < 4; ++r) {
        pp[(size_t)(o0 + mt * 16 + quad * 4 + r) * 4096 + n0 + nt * 16 + ln] =
            ((const float*)&acc[mt][nt])[r];
      }
    }
  }
}

// ---------------- fusion combine: out = p0+p1+p2 + bias -------------------------
__global__ __launch_bounds__(256) void fus_combine_kernel(const float* __restrict__ part,
    const float* __restrict__ bias, float* __restrict__ out) {
  int id = blockIdx.x * 256 + threadIdx.x;          // float4 index
  int o = id >> 10;
  float4 v0 = *(const float4*)(part + id * 4);
  float4 v1 = *(const float4*)(part + 1048576 + id * 4);
  float4 v2 = *(const float4*)(part + 2097152 + id * 4);
  float bs = bias[o];
  float4 r;
  r.x = v0.x + v1.x + v2.x + bs;
  r.y = v0.y + v1.y + v2.y + bs;
  r.z = v0.z + v1.z + v2.z + bs;
  r.w = v0.w + v1.w + v2.w + bs;
  *(float4*)(out + id * 4) = r;
}

extern "C" void kernel_launch(void* const* d_in, const int* in_sizes, int n_in,
                              void* d_out, int out_size, void* d_ws, size_t ws_size,
                              hipStream_t stream) {
  const float* x     = (const float*)d_in[0];
  const float* dw_w  = (const float*)d_in[1];
  const float* dw_b  = (const float*)d_in[2];
  const float* pw_w  = (const float*)d_in[3];
  const float* pw_b  = (const float*)d_in[4];
  const float* pos_w = (const float*)d_in[5];
  const float* pos_b = (const float*)d_in[6];
  const float* fus_w = (const float*)d_in[7];
  const float* fus_b = (const float*)d_in[8];
  float* out = (float*)d_out;
  float* ws = (float*)d_ws;

  // ws layout (floats), total 12,058,624 fl = 46.0 MB (aliasing noted inline)
  float* xdwAll = ws;                        // 1,376,256  [attn s2/s4 bf16 partials later]
  float* posAll = ws + 1376256;              // 1,376,256  [lsum1/2/4 + out2/out4 later]
  float* accpF  = ws + 2752512;              // 4,194,304  [xs2/xs4 early; s1 bf16 partials; fusion part]
  unsigned short* xdwT = (unsigned short*)(ws + 6946816);   // 1,376,256 us
  unsigned short* posT = (unsigned short*)(ws + 7634944);   // 1,376,256 us
  unsigned short* qkvT = (unsigned short*)(ws + 8323072);   // 2,752,512 us
  unsigned short* Vb   = (unsigned short*)(ws + 9699328);   // 1,376,256 us
  unsigned short* catT = (unsigned short*)(ws + 10387456);  // 3,145,728 us [Wb early]
  unsigned short* Wf   = (unsigned short*)(ws + 11960320);  //   196,608 us

  float* xs2 = accpF;                        // dead before attn-s1 writes accp
  float* xs4 = accpF + 262144;
  unsigned short* Wb = catT;                 // dead before build_catT writes catT
  unsigned short* accp = (unsigned short*)accpF;            // 8,388,608 us (8 splits)
  float* lsump1 = posAll;                    // 262,144 (8sp x 8h x 4096)
  float* lsump2 = posAll + 262144;           // 65,536
  float* lsump4 = posAll + 327680;           // 8,192
  float* out2   = posAll + 335872;           // 262,144
  float* out4   = posAll + 598016;           // 65,536
  unsigned short* p2 = (unsigned short*)xdwAll;             // 2,097,152 us (8 splits)
  unsigned short* p4 = (unsigned short*)xdwAll + 2097152;   //   262,144 us (4 splits)
  float* part = accpF;                       // fusion partials (accp dead then)

  prep_kernel<<<2048, 256, 0, stream>>>(x, pw_w, fus_w, xs2, xs4, Wb, Wf);
  dwconv_all_kernel<<<5376, 256, 0, stream>>>(x, xs2, xs4, dw_w, dw_b, pos_w, pos_b,
                                              xdwAll, posAll);
  transpose_all_kernel<<<672, 256, 0, stream>>>(xdwAll, posAll, xdwT, posT);
  gemm_qkv_all<<<dim3(12, 84), 256, 0, stream>>>(Wb, xdwT, pw_b, posT, qkvT, Vb);

  attn_all_kernel<<<dim3(32, 8, 20), 256, 0, stream>>>(qkvT, Vb, accp, p2, p4,
                                                       lsump1, lsump2, lsump4);
  combine24_kernel<<<1280, 256, 0, stream>>>(p2, lsump2, p4, lsump4, out2, out4);

  build_catT_kernel<<<dim3(64, 12), 256, 0, stream>>>(accp, lsump1, out2, out4, catT);
  gemm_fus_mfma<<<dim3(4, 64, 3), 256, 0, stream>>>(Wf, catT, part);
  fus_combine_kernel<<<1024, 256, 0, stream>>>(part, fus_b, out);
}

// Round 8
// 168.520 us; speedup vs baseline: 1.2967x; 1.2967x over previous
//
#include <hip/hip_runtime.h>
#include <math.h>

#define DIM 256
#define HEADS 8
#define HD 32
// log2(e)/sqrt(32): folded into stored Q so attention uses native exp2
#define QSCALE 0.25504526770295183f

typedef __attribute__((ext_vector_type(8))) short bf16x8;
typedef __attribute__((ext_vector_type(4))) float f32x4;

#if __has_builtin(__builtin_amdgcn_exp2f)
#define EXP2(x) __builtin_amdgcn_exp2f(x)
#else
#define EXP2(x) __expf((x) * 0.6931471805599453f)
#endif

__device__ __forceinline__ unsigned short f2bf(float f) {
  unsigned int u = __float_as_uint(f);
  unsigned int r = u + 0x7fff + ((u >> 16) & 1);   // round-to-nearest-even
  return (unsigned short)(r >> 16);
}
__device__ __forceinline__ float bf2f(unsigned short u) {
  return __uint_as_float(((unsigned int)u) << 16);
}

// ---------------- prep: both avgpools + both weight cvts in one launch ----------
__global__ __launch_bounds__(256) void prep_kernel(const float* __restrict__ x,
    const float* __restrict__ pw_w, const float* __restrict__ fus_w,
    float* __restrict__ xs2, float* __restrict__ xs4,
    unsigned short* __restrict__ Wb, unsigned short* __restrict__ Wf) {
  const int gx = blockIdx.x, t = threadIdx.x;
  if (gx < 1024) {                                  // avgpool s=2 -> 256x32x32
    int id = gx * 256 + t;
    int c = id >> 10, n = id & 1023;
    int y = (n >> 5) << 1, x0 = (n & 31) << 1;
    const float* b = x + c * 4096 + y * 64 + x0;
    xs2[id] = (b[0] + b[1] + b[64] + b[65]) * 0.25f;
  } else if (gx < 1280) {                           // avgpool s=4 -> 256x16x16
    int id = (gx - 1024) * 256 + t;
    int c = id >> 8, n = id & 255;
    int y = (n >> 4) << 2, x0 = (n & 15) << 2;
    const float* b = x + c * 4096 + y * 64 + x0;
    float s = 0.f;
    #pragma unroll
    for (int dy = 0; dy < 4; ++dy)
      #pragma unroll
      for (int dx = 0; dx < 4; ++dx) s += b[dy * 64 + dx];
    xs4[id] = s * 0.0625f;
  } else if (gx < 1856) {                           // cvt pw_w -> Wb (589824 fl)
    int id = (gx - 1280) * 256 + t;
    float4 v = *(const float4*)(pw_w + id * 4);
    ushort4 st; st.x = f2bf(v.x); st.y = f2bf(v.y); st.z = f2bf(v.z); st.w = f2bf(v.w);
    *(ushort4*)(Wb + id * 4) = st;
  } else {                                          // cvt fus_w -> Wf (196608 fl)
    int id = (gx - 1856) * 256 + t;
    float4 v = *(const float4*)(fus_w + id * 4);
    ushort4 st; st.x = f2bf(v.x); st.y = f2bf(v.y); st.z = f2bf(v.z); st.w = f2bf(v.w);
    *(ushort4*)(Wf + id * 4) = st;
  }
}

// ---------------- dwconv (dw + pos), all 3 scales in one launch -----------------
__global__ __launch_bounds__(256) void dwconv_all_kernel(const float* __restrict__ x,
    const float* __restrict__ xs2, const float* __restrict__ xs4,
    const float* __restrict__ dw_w, const float* __restrict__ dw_b,
    const float* __restrict__ pos_w, const float* __restrict__ pos_b,
    float* __restrict__ xdwAll, float* __restrict__ posAll) {
  int gx = blockIdx.x;
  const float* src;
  int lgHs, wo, soff;
  if (gx < 4096)      { src = x;   lgHs = 6; wo = 0; soff = 0; }
  else if (gx < 5120) { src = xs2; lgHs = 5; wo = 1; soff = 1048576; gx -= 4096; }
  else                { src = xs4; lgHs = 4; wo = 2; soff = 1310720; gx -= 5120; }
  int Hs = 1 << lgHs;
  int Ns = Hs * Hs;
  int id = gx * 256 + threadIdx.x;                  // c * Ns + n  (within scale)
  int c = id >> (2 * lgHs);
  int n = id & (Ns - 1);
  int y = n >> lgHs, xx0 = n & (Hs - 1);
  const float* w1 = dw_w + wo * 2304 + c * 9;
  const float* w2 = pos_w + wo * 2304 + c * 9;
  const float* sb = src + c * Ns;
  float s1 = dw_b[wo * 256 + c], s2 = pos_b[wo * 256 + c];
  #pragma unroll
  for (int ky = 0; ky < 3; ++ky) {
    int yy = y + ky - 1;
    bool yok = (yy >= 0) && (yy < Hs);
    #pragma unroll
    for (int kx = 0; kx < 3; ++kx) {
      int xc = xx0 + kx - 1;
      bool ok = yok && (xc >= 0) && (xc < Hs);
      float v = ok ? sb[yy * Hs + xc] : 0.f;
      s1 += v * w1[ky * 3 + kx];
      s2 += v * w2[ky * 3 + kx];
    }
  }
  xdwAll[soff + id] = s1;
  posAll[soff + id] = s2;
}

// ---------------- transpose + cvt for all scales / both sources ----------------
// fp32 [256][Ns] -> bf16 [Ns][256]
__global__ __launch_bounds__(256) void transpose_all_kernel(const float* __restrict__ xdwAll,
    const float* __restrict__ posAll, unsigned short* __restrict__ xdwT,
    unsigned short* __restrict__ posT) {
  __shared__ unsigned short lds[64][72];
  int b = blockIdx.x;
  int N, soff, nx;
  if (b < 512)      { N = 4096; soff = 0;       nx = 64; }
  else if (b < 640) { N = 1024; soff = 1048576; nx = 16; b -= 512; }
  else              { N = 256;  soff = 1310720; nx = 4;  b -= 640; }
  const int z = b / (nx * 4);
  const int rem = b % (nx * 4);
  const int c0 = (rem / nx) * 64;
  const int n0 = (rem % nx) * 64;
  const float* src = (z ? posAll : xdwAll) + soff;
  unsigned short* dst = (z ? posT : xdwT) + soff;
  const int t = threadIdx.x;
  #pragma unroll
  for (int p = 0; p < 4; ++p) {
    int c = p * 16 + (t >> 4);
    int nn = (t & 15) * 4;
    float4 v = *(const float4*)(src + (size_t)(c0 + c) * N + n0 + nn);
    lds[nn + 0][c] = f2bf(v.x);
    lds[nn + 1][c] = f2bf(v.y);
    lds[nn + 2][c] = f2bf(v.z);
    lds[nn + 3][c] = f2bf(v.w);
  }
  __syncthreads();
  int n = t >> 2, seg = (t & 3) * 16;
  *(bf16x8*)(dst + (size_t)(n0 + n) * 256 + c0 + seg)     = *(const bf16x8*)&lds[n][seg];
  *(bf16x8*)(dst + (size_t)(n0 + n) * 256 + c0 + seg + 8) = *(const bf16x8*)&lds[n][seg + 8];
}

// ---------------- QKV GEMM via bf16 MFMA -> MFMA-FRAGMENT-layout outputs --------
// Q/K frag: block per (h, 16-row n/m tile): 64 lanes x 8 shorts, lane=(d>>3)*16+(row&15),
//           elem j = d&7.  V frag: block per (h, 32-col m chunk, 16-row d tile):
//           lane=((m&31)>>3)*16+(d&15), elem j = m&7.
// Every attention fragment load becomes contiguous base+lane*16B.
__global__ __launch_bounds__(256) void gemm_qkv_all(const unsigned short* __restrict__ WbA,
    const unsigned short* __restrict__ xdwTA, const float* __restrict__ biasA,
    const unsigned short* __restrict__ posTA, unsigned short* __restrict__ Qf,
    unsigned short* __restrict__ Kf, unsigned short* __restrict__ Vf) {
  int by = blockIdx.y;
  int Ns, off;                                      // off = frag/element offset per scale
  const unsigned short *Wb, *xdwT, *posT;
  const float* bias;
  if (by < 64) {
    Ns = 4096; off = 0;
    Wb = WbA; bias = biasA;
  } else if (by < 80) {
    Ns = 1024; off = 1048576; by -= 64;
    Wb = WbA + 196608; bias = biasA + 768;
  } else {
    Ns = 256; off = 1310720; by -= 80;
    Wb = WbA + 393216; bias = biasA + 1536;
  }
  xdwT = xdwTA + off; posT = posTA + off;
  const int t = threadIdx.x;
  const int wave = t >> 6, lane = t & 63;
  const int ln = lane & 15, quad = lane >> 4;
  const int o0 = blockIdx.x * 64 + (wave & 1) * 32;
  const int n0 = by * 64 + (wave >> 1) * 32;
  const unsigned short* a0 = Wb + (size_t)(o0 + ln) * 256 + quad * 8;
  const unsigned short* a1 = a0 + 16 * 256;
  const unsigned short* b0 = xdwT + (size_t)(n0 + ln) * 256 + quad * 8;
  const unsigned short* b1 = b0 + 16 * 256;
  f32x4 acc[2][2] = {};
  #pragma unroll
  for (int ks = 0; ks < 8; ++ks) {
    bf16x8 af0 = *(const bf16x8*)(a0 + ks * 32);
    bf16x8 af1 = *(const bf16x8*)(a1 + ks * 32);
    bf16x8 bv0 = *(const bf16x8*)(b0 + ks * 32);
    bf16x8 bv1 = *(const bf16x8*)(b1 + ks * 32);
    acc[0][0] = __builtin_amdgcn_mfma_f32_16x16x32_bf16(af0, bv0, acc[0][0], 0, 0, 0);
    acc[0][1] = __builtin_amdgcn_mfma_f32_16x16x32_bf16(af0, bv1, acc[0][1], 0, 0, 0);
    acc[1][0] = __builtin_amdgcn_mfma_f32_16x16x32_bf16(af1, bv0, acc[1][0], 0, 0, 0);
    acc[1][1] = __builtin_amdgcn_mfma_f32_16x16x32_bf16(af1, bv1, acc[1][1], 0, 0, 0);
  }
  const int cat = blockIdx.x >> 2;                  // 0=q 1=k 2=v
  #pragma unroll
  for (int mt = 0; mt < 2; ++mt) {
    int ot = o0 + mt * 16 + quad * 4;
    float bs0 = bias[ot], bs1 = bias[ot + 1], bs2 = bias[ot + 2], bs3 = bias[ot + 3];
    #pragma unroll
    for (int nt = 0; nt < 2; ++nt) {
      int nn = n0 + nt * 16 + ln;
      f32x4 v = acc[mt][nt];
      v.x += bs0; v.y += bs1; v.z += bs2; v.w += bs3;
      if (cat < 2) {
        int c = ot & 255;
        ushort4 p4 = *(const ushort4*)(posT + (size_t)nn * 256 + c);
        v.x += bf2f(p4.x); v.y += bf2f(p4.y); v.z += bf2f(p4.z); v.w += bf2f(p4.w);
        if (cat == 0) { v.x *= QSCALE; v.y *= QSCALE; v.z *= QSCALE; v.w *= QSCALE; }
        ushort4 st;
        st.x = f2bf(v.x); st.y = f2bf(v.y); st.z = f2bf(v.z); st.w = f2bf(v.w);
        int hh = c >> 5, d = c & 31;
        unsigned short* dst = (cat == 0 ? Qf : Kf) + off;
        size_t a = ((size_t)(hh * (Ns >> 4) + (nn >> 4)) * 64 + (d >> 3) * 16 + (nn & 15)) * 8
                   + (d & 7);
        *(ushort4*)(dst + a) = st;
      } else {
        int c = ot - 512;
        int hh = c >> 5, d = c & 31;
        int dt = d >> 4, lnv = d & 15;
        size_t a = ((((size_t)hh * (Ns >> 5) + (nn >> 5)) * 2 + dt) * 64
                    + ((nn & 31) >> 3) * 16) * 8 + (nn & 7);
        unsigned short* dst = Vf + off;
        dst[a + (size_t)(lnv + 0) * 8] = f2bf(v.x);
        dst[a + (size_t)(lnv + 1) * 8] = f2bf(v.y);
        dst[a + (size_t)(lnv + 2) * 8] = f2bf(v.z);
        dst[a + (size_t)(lnv + 3) * 8] = f2bf(v.w);
      }
    }
  }
}

// ---------------- attention: all scales one launch, fragment-layout loads -------
// z 0..7: s1 splits; z 8..15: s2 splits (x<8); z 16..19: s4 splits (x<2).
// All global fragment loads are contiguous base+lane*16B (no gathers).
__global__ __launch_bounds__(256) void attn_all_kernel(
    const unsigned short* __restrict__ Qf, const unsigned short* __restrict__ Kf,
    const unsigned short* __restrict__ Vf,
    unsigned short* __restrict__ accp1, unsigned short* __restrict__ p2,
    unsigned short* __restrict__ p4, float* __restrict__ ls1,
    float* __restrict__ ls2, float* __restrict__ ls4) {
  __shared__ unsigned short pt_lds[4 * 32 * 72];    // wave-private P^T [n][m], pad 72
  const int z = blockIdx.z;
  unsigned short* accp;
  float* lsump;
  int Ns, lgMs, sp, off;
  if (z < 8) {
    accp = accp1; lsump = ls1; Ns = 4096; lgMs = 9; sp = z; off = 0;
  } else if (z < 16) {
    if (blockIdx.x >= 8) return;
    accp = p2; lsump = ls2; Ns = 1024; lgMs = 7; sp = z - 8; off = 1048576;
  } else {
    if (blockIdx.x >= 2) return;
    accp = p4; lsump = ls4; Ns = 256; lgMs = 6; sp = z - 16; off = 1310720;
  }
  const int t = threadIdx.x;
  const int wave = t >> 6, lane = t & 63;
  const int ln = lane & 15, quad = lane >> 4;
  const int h = blockIdx.y;
  const int n0 = blockIdx.x * 128 + wave * 32;
  const unsigned short* qp = Qf + off
      + ((size_t)(h * (Ns >> 4) + (n0 >> 4)) * 64 + lane) * 8;
  bf16x8 qf0 = *(const bf16x8*)(qp);
  bf16x8 qf1 = *(const bf16x8*)(qp + 512);
  unsigned short* ptw = pt_lds + wave * (32 * 72);
  f32x4 acc[2][2] = {};
  float lsum0 = 0.f, lsum1 = 0.f;
  const f32x4 zero = {0.f, 0.f, 0.f, 0.f};
  const int m0s = sp << lgMs;
  const int nch = 1 << (lgMs - 6);
  const unsigned short* kp = Kf + off
      + ((size_t)(h * (Ns >> 4) + (m0s >> 4)) * 64 + lane) * 8;
  const unsigned short* vp = Vf + off
      + (((size_t)h * (Ns >> 5) + (m0s >> 5)) * 128 + lane) * 8;
  for (int ch = 0; ch < nch; ++ch) {
    const unsigned short* kc = kp + ch * 2048;
    const unsigned short* vc = vp + ch * 2048;
    bf16x8 kf0 = *(const bf16x8*)(kc);
    bf16x8 kf1 = *(const bf16x8*)(kc + 512);
    bf16x8 kf2 = *(const bf16x8*)(kc + 1024);
    bf16x8 kf3 = *(const bf16x8*)(kc + 1536);
    bf16x8 vf00 = *(const bf16x8*)(vc);          // ks0, dt0
    bf16x8 vf10 = *(const bf16x8*)(vc + 512);    // ks0, dt1
    bf16x8 vf01 = *(const bf16x8*)(vc + 1024);   // ks1, dt0
    bf16x8 vf11 = *(const bf16x8*)(vc + 1536);   // ks1, dt1
    f32x4 s[4][2];
    s[0][0] = __builtin_amdgcn_mfma_f32_16x16x32_bf16(kf0, qf0, zero, 0, 0, 0);
    s[0][1] = __builtin_amdgcn_mfma_f32_16x16x32_bf16(kf0, qf1, zero, 0, 0, 0);
    s[1][0] = __builtin_amdgcn_mfma_f32_16x16x32_bf16(kf1, qf0, zero, 0, 0, 0);
    s[1][1] = __builtin_amdgcn_mfma_f32_16x16x32_bf16(kf1, qf1, zero, 0, 0, 0);
    s[2][0] = __builtin_amdgcn_mfma_f32_16x16x32_bf16(kf2, qf0, zero, 0, 0, 0);
    s[2][1] = __builtin_amdgcn_mfma_f32_16x16x32_bf16(kf2, qf1, zero, 0, 0, 0);
    s[3][0] = __builtin_amdgcn_mfma_f32_16x16x32_bf16(kf3, qf0, zero, 0, 0, 0);
    s[3][1] = __builtin_amdgcn_mfma_f32_16x16x32_bf16(kf3, qf1, zero, 0, 0, 0);
    #pragma unroll
    for (int mt = 0; mt < 4; ++mt) {
      #pragma unroll
      for (int nt = 0; nt < 2; ++nt) {
        float e0 = EXP2(s[mt][nt].x);
        float e1 = EXP2(s[mt][nt].y);
        float e2 = EXP2(s[mt][nt].z);
        float e3 = EXP2(s[mt][nt].w);
        if (nt == 0) lsum0 += (e0 + e1) + (e2 + e3);
        else         lsum1 += (e0 + e1) + (e2 + e3);
        uint2 pk;                                   // bf16-truncate pack, 1 op/pair
        pk.x = __builtin_amdgcn_perm(__float_as_uint(e1), __float_as_uint(e0), 0x07060302);
        pk.y = __builtin_amdgcn_perm(__float_as_uint(e3), __float_as_uint(e2), 0x07060302);
        *(uint2*)&ptw[(nt * 16 + ln) * 72 + mt * 16 + quad * 4] = pk;
      }
    }
    #pragma unroll
    for (int ks = 0; ks < 2; ++ks) {
      bf16x8 pf0 = *(const bf16x8*)&ptw[ln * 72 + ks * 32 + quad * 8];
      bf16x8 pf1 = *(const bf16x8*)&ptw[(16 + ln) * 72 + ks * 32 + quad * 8];
      bf16x8 va = ks ? vf01 : vf00;
      bf16x8 vbf = ks ? vf11 : vf10;
      acc[0][0] = __builtin_amdgcn_mfma_f32_16x16x32_bf16(va, pf0, acc[0][0], 0, 0, 0);
      acc[0][1] = __builtin_amdgcn_mfma_f32_16x16x32_bf16(va, pf1, acc[0][1], 0, 0, 0);
      acc[1][0] = __builtin_amdgcn_mfma_f32_16x16x32_bf16(vbf, pf0, acc[1][0], 0, 0, 0);
      acc[1][1] = __builtin_amdgcn_mfma_f32_16x16x32_bf16(vbf, pf1, acc[1][1], 0, 0, 0);
    }
  }
  lsum0 += __shfl_xor(lsum0, 16, 64);
  lsum0 += __shfl_xor(lsum0, 32, 64);
  lsum1 += __shfl_xor(lsum1, 16, 64);
  lsum1 += __shfl_xor(lsum1, 32, 64);
  unsigned short* ap = accp + ((size_t)sp * 256 + h * 32) * Ns;
  #pragma unroll
  for (int dt = 0; dt < 2; ++dt) {
    #pragma unroll
    for (int r = 0; r < 4; ++r) {
      int cl = dt * 16 + quad * 4 + r;
      ap[(size_t)cl * Ns + n0 + ln]      = f2bf(((const float*)&acc[dt][0])[r]);
      ap[(size_t)cl * Ns + n0 + 16 + ln] = f2bf(((const float*)&acc[dt][1])[r]);
    }
  }
  if (lane < 16) {
    float* lp = lsump + ((size_t)sp * 8 + h) * Ns + n0;
    lp[lane]      = lsum0;
    lp[16 + lane] = lsum1;
  }
}

// ---------------- combine s2 (8 splits) + s4 (4 splits) in one launch -----------
__global__ __launch_bounds__(256) void combine24_kernel(const unsigned short* __restrict__ p2,
    const float* __restrict__ ls2, const unsigned short* __restrict__ p4,
    const float* __restrict__ ls4, float* __restrict__ out2, float* __restrict__ out4) {
  int id = blockIdx.x * 256 + threadIdx.x;
  if (id < 262144) {                                // s2: 256 x 1024
    int n = id & 1023, h = id >> 15;
    float v = 0.f, d = 0.f;
    #pragma unroll
    for (int sp = 0; sp < 8; ++sp) {
      v += bf2f(p2[sp * 262144 + id]);
      d += ls2[sp * 8192 + h * 1024 + n];
    }
    out2[id] = v / d;
  } else {                                          // s4: 256 x 256
    int idl = id - 262144;
    int n = idl & 255, h = idl >> 13;
    float v = 0.f, d = 0.f;
    #pragma unroll
    for (int sp = 0; sp < 4; ++sp) {
      v += bf2f(p4[sp * 65536 + idl]);
      d += ls4[sp * 2048 + h * 256 + n];
    }
    out4[idl] = v / d;
  }
}

// ---------------- build catT bf16 [4096][768] directly --------------------------
__global__ __launch_bounds__(256) void build_catT_kernel(const unsigned short* __restrict__ accp,
    const float* __restrict__ lsum1, const float* __restrict__ out2,
    const float* __restrict__ out4, unsigned short* __restrict__ catT) {
  __shared__ unsigned short lds[64][72];
  const int t = threadIdx.x;
  const int n0 = blockIdx.x * 64;
  const int by = blockIdx.y;
  const int c0 = by * 64;
  if (by < 4) {
    #pragma unroll
    for (int p = 0; p < 4; ++p) {
      int ct = p * 16 + (t >> 4);
      int c = c0 + ct;
      int h = c >> 5;
      int nn = (t & 15) * 4;
      float vs[4] = {0.f, 0.f, 0.f, 0.f};
      float ds[4] = {0.f, 0.f, 0.f, 0.f};
      #pragma unroll
      for (int sp = 0; sp < 8; ++sp) {
        ushort4 a = *(const ushort4*)(accp + (size_t)sp * 1048576 + (size_t)c * 4096 + n0 + nn);
        vs[0] += bf2f(a.x); vs[1] += bf2f(a.y); vs[2] += bf2f(a.z); vs[3] += bf2f(a.w);
        float4 dd = *(const float4*)(lsum1 + (size_t)sp * 32768 + (size_t)h * 4096 + n0 + nn);
        ds[0] += dd.x; ds[1] += dd.y; ds[2] += dd.z; ds[3] += dd.w;
      }
      lds[nn + 0][ct] = f2bf(vs[0] / ds[0]);
      lds[nn + 1][ct] = f2bf(vs[1] / ds[1]);
      lds[nn + 2][ct] = f2bf(vs[2] / ds[2]);
      lds[nn + 3][ct] = f2bf(vs[3] / ds[3]);
    }
  } else {
    const bool s2 = by < 8;
    const float* src = s2 ? out2 : out4;
    const int Hs = s2 ? 32 : 16;
    const int coff = s2 ? 256 : 512;
    const float sc = (float)Hs / 64.0f;
    #pragma unroll
    for (int p = 0; p < 4; ++p) {
      int ct = p * 16 + (t >> 4);
      const float* s = src + (size_t)(c0 - coff + ct) * Hs * Hs;
      int nn = (t & 15) * 4;
      #pragma unroll
      for (int i = 0; i < 4; ++i) {
        int n = n0 + nn + i;
        int y = n >> 6, x = n & 63;
        float fy = ((float)y + 0.5f) * sc - 0.5f;
        float fx = ((float)x + 0.5f) * sc - 0.5f;
        float fy0 = floorf(fy), fx0 = floorf(fx);
        int y0 = (int)fy0, x0 = (int)fx0;
        float ty = fy - fy0, tx = fx - fx0;
        int y0c = min(max(y0, 0), Hs - 1), y1c = min(max(y0 + 1, 0), Hs - 1);
        int x0c = min(max(x0, 0), Hs - 1), x1c = min(max(x0 + 1, 0), Hs - 1);
        float v00 = s[y0c * Hs + x0c], v01 = s[y0c * Hs + x1c];
        float v10 = s[y1c * Hs + x0c], v11 = s[y1c * Hs + x1c];
        float v0 = v00 + (v01 - v00) * tx;
        float v1 = v10 + (v11 - v10) * tx;
        lds[nn + i][ct] = f2bf(v0 + (v1 - v0) * ty);
      }
    }
  }
  __syncthreads();
  int n = t >> 2, seg = (t & 3) * 16;
  *(bf16x8*)(catT + (size_t)(n0 + n) * 768 + c0 + seg)     = *(const bf16x8*)&lds[n][seg];
  *(bf16x8*)(catT + (size_t)(n0 + n) * 768 + c0 + seg + 8) = *(const bf16x8*)&lds[n][seg + 8];
}

// ---------------- fusion GEMM via bf16 MFMA, split-K=3 --------------------------
__global__ __launch_bounds__(256) void gemm_fus_mfma(const unsigned short* __restrict__ Wf,
    const unsigned short* __restrict__ catT, float* __restrict__ part) {
  const int t = threadIdx.x;
  const int wave = t >> 6, lane = t & 63;
  const int ln = lane & 15, quad = lane >> 4;
  const int o0 = blockIdx.x * 64 + (wave & 1) * 32;
  const int n0 = blockIdx.y * 64 + (wave >> 1) * 32;
  const int sp = blockIdx.z;
  const int k0 = sp * 256;
  const unsigned short* a0 = Wf + (size_t)(o0 + ln) * 768 + k0 + quad * 8;
  const unsigned short* a1 = a0 + 16 * 768;
  const unsigned short* b0 = catT + (size_t)(n0 + ln) * 768 + k0 + quad * 8;
  const unsigned short* b1 = b0 + 16 * 768;
  f32x4 acc[2][2] = {};
  #pragma unroll
  for (int ks = 0; ks < 8; ++ks) {
    bf16x8 af0 = *(const bf16x8*)(a0 + ks * 32);
    bf16x8 af1 = *(const bf16x8*)(a1 + ks * 32);
    bf16x8 bv0 = *(const bf16x8*)(b0 + ks * 32);
    bf16x8 bv1 = *(const bf16x8*)(b1 + ks * 32);
    acc[0][0] = __builtin_amdgcn_mfma_f32_16x16x32_bf16(af0, bv0, acc[0][0], 0, 0, 0);
    acc[0][1] = __builtin_amdgcn_mfma_f32_16x16x32_bf16(af0, bv1, acc[0][1], 0, 0, 0);
    acc[1][0] = __builtin_amdgcn_mfma_f32_16x16x32_bf16(af1, bv0, acc[1][0], 0, 0, 0);
    acc[1][1] = __builtin_amdgcn_mfma_f32_16x16x32_bf16(af1, bv1, acc[1][1], 0, 0, 0);
  }
  float* pp = part + (size_t)sp * 1048576;
  #pragma unroll
  for (int mt = 0; mt < 2; ++mt) {
    #pragma unroll
    for (int nt = 0; nt < 2; ++nt) {
      #pragma unroll
      for (int r = 0; r < 4; ++r) {
        pp[(size_t)(o0 + mt * 16 + quad * 4 + r) * 4096 + n0 + nt * 16 + ln] =
            ((const float*)&acc[mt][nt])[r];
      }
    }
  }
}

// ---------------- fusion combine: out = p0+p1+p2 + bias -------------------------
__global__ __launch_bounds__(256) void fus_combine_kernel(const float* __restrict__ part,
    const float* __restrict__ bias, float* __restrict__ out) {
  int id = blockIdx.x * 256 + threadIdx.x;          // float4 index
  int o = id >> 10;
  float4 v0 = *(const float4*)(part + id * 4);
  float4 v1 = *(const float4*)(part + 1048576 + id * 4);
  float4 v2 = *(const float4*)(part + 2097152 + id * 4);
  float bs = bias[o];
  float4 r;
  r.x = v0.x + v1.x + v2.x + bs;
  r.y = v0.y + v1.y + v2.y + bs;
  r.z = v0.z + v1.z + v2.z + bs;
  r.w = v0.w + v1.w + v2.w + bs;
  *(float4*)(out + id * 4) = r;
}

extern "C" void kernel_launch(void* const* d_in, const int* in_sizes, int n_in,
                              void* d_out, int out_size, void* d_ws, size_t ws_size,
                              hipStream_t stream) {
  const float* x     = (const float*)d_in[0];
  const float* dw_w  = (const float*)d_in[1];
  const float* dw_b  = (const float*)d_in[2];
  const float* pw_w  = (const float*)d_in[3];
  const float* pw_b  = (const float*)d_in[4];
  const float* pos_w = (const float*)d_in[5];
  const float* pos_b = (const float*)d_in[6];
  const float* fus_w = (const float*)d_in[7];
  const float* fus_b = (const float*)d_in[8];
  float* out = (float*)d_out;
  float* ws = (float*)d_ws;

  // ws layout (floats), total 12,058,624 fl = 46.0 MB (aliasing noted inline)
  float* xdwAll = ws;                        // 1,376,256  [attn s2/s4 bf16 partials later]
  float* posAll = ws + 1376256;              // 1,376,256  [lsum1/2/4 + out2/out4 later]
  float* accpF  = ws + 2752512;              // 4,194,304  [xs2/xs4 early; s1 bf16 partials; fusion part]
  unsigned short* xdwT = (unsigned short*)(ws + 6946816);   // 1,376,256 us
  unsigned short* posT = (unsigned short*)(ws + 7634944);   // 1,376,256 us
  unsigned short* Qf   = (unsigned short*)(ws + 8323072);   // 1,376,256 us
  unsigned short* Kf   = Qf + 1376256;                      // 1,376,256 us
  unsigned short* Vf   = (unsigned short*)(ws + 9699328);   // 1,376,256 us
  unsigned short* catT = (unsigned short*)(ws + 10387456);  // 3,145,728 us [Wb early]
  unsigned short* Wf   = (unsigned short*)(ws + 11960320);  //   196,608 us

  float* xs2 = accpF;                        // dead before attn-s1 writes accp
  float* xs4 = accpF + 262144;
  unsigned short* Wb = catT;                 // dead before build_catT writes catT
  unsigned short* accp = (unsigned short*)accpF;            // 8,388,608 us (8 splits)
  float* lsump1 = posAll;                    // 262,144 (8sp x 8h x 4096)
  float* lsump2 = posAll + 262144;           // 65,536
  float* lsump4 = posAll + 327680;           // 8,192
  float* out2   = posAll + 335872;           // 262,144
  float* out4   = posAll + 598016;           // 65,536
  unsigned short* p2 = (unsigned short*)xdwAll;             // 2,097,152 us (8 splits)
  unsigned short* p4 = (unsigned short*)xdwAll + 2097152;   //   262,144 us (4 splits)
  float* part = accpF;                       // fusion partials (accp dead then)

  prep_kernel<<<2048, 256, 0, stream>>>(x, pw_w, fus_w, xs2, xs4, Wb, Wf);
  dwconv_all_kernel<<<5376, 256, 0, stream>>>(x, xs2, xs4, dw_w, dw_b, pos_w, pos_b,
                                              xdwAll, posAll);
  transpose_all_kernel<<<672, 256, 0, stream>>>(xdwAll, posAll, xdwT, posT);
  gemm_qkv_all<<<dim3(12, 84), 256, 0, stream>>>(Wb, xdwT, pw_b, posT, Qf, Kf, Vf);

  attn_all_kernel<<<dim3(32, 8, 20), 256, 0, stream>>>(Qf, Kf, Vf, accp, p2, p4,
                                                       lsump1, lsump2, lsump4);
  combine24_kernel<<<1280, 256, 0, stream>>>(p2, lsump2, p4, lsump4, out2, out4);

  build_catT_kernel<<<dim3(64, 12), 256, 0, stream>>>(accp, lsump1, out2, out4, catT);
  gemm_fus_mfma<<<dim3(4, 64, 3), 256, 0, stream>>>(Wf, catT, part);
  fus_combine_kernel<<<1024, 256, 0, stream>>>(part, fus_b, out);
}